// Round 1
// 326.541 us; speedup vs baseline: 1.2293x; 1.2293x over previous
//
#include <hip/hip_runtime.h>

// ---------- types ----------
typedef __attribute__((ext_vector_type(8))) short short8;   // 8 x bf16
typedef __attribute__((ext_vector_type(4))) short short4v;  // 4 x bf16
typedef __attribute__((ext_vector_type(2))) int int2v;
typedef __attribute__((ext_vector_type(4))) float float4v;

#define MFMA16(a, b, c) __builtin_amdgcn_mfma_f32_16x16x32_bf16((a), (b), (c), 0, 0, 0)

__device__ __forceinline__ short f2bf(float f) {  // RNE fp32 -> bf16
  unsigned u = __float_as_uint(f);
  u += 0x7fffu + ((u >> 16) & 1u);
  return (short)(u >> 16);
}

__device__ __forceinline__ int pkbf(float a, float b) {
  return (int)(unsigned short)f2bf(a) | (((int)(unsigned short)f2bf(b)) << 16);
}

// packed fp32x2 -> bf16x2 (RNE) in one VALU op; compiler can't derive this
// from the bit-twiddle form.
__device__ __forceinline__ int cvtpk(float a, float b) {
  int r;
  asm("v_cvt_pk_bf16_f32 %0, %1, %2" : "=v"(r) : "v"(a), "v"(b));
  return r;
}

// async global->LDS, 16B per lane; LDS dest = wave-uniform base + lane*16
__device__ __forceinline__ void glds16(const short* g, short* l) {
  __builtin_amdgcn_global_load_lds(
      (const __attribute__((address_space(1))) void*)g,
      (__attribute__((address_space(3))) void*)l, 16, 0, 0);
}

// ---------- fused fp32 -> bf16 cast (all 9 tensors, one launch) ----------
struct CastSeg { const float* src; short* dst; int n4; };
struct CastArgs { CastSeg seg[9]; int start[10]; };

__global__ __launch_bounds__(256) void castk(CastArgs a) {
  int blk = blockIdx.x;
  int si = 0;
#pragma unroll
  for (int i = 1; i < 9; i++) si += (blk >= a.start[i]);
  int i = (blk - a.start[si]) * 256 + threadIdx.x;
  if (i >= a.seg[si].n4) return;
  float4v f = ((const float4v*)a.seg[si].src)[i];
  short4v o;
  o[0] = f2bf(f[0]); o[1] = f2bf(f[1]); o[2] = f2bf(f[2]); o[3] = f2bf(f[3]);
  ((short4v*)a.seg[si].dst)[i] = o;
}

// ---------- tiled MFMA GEMM (m97 structure) ----------
// out[m, ocol+n] = A(M,K) @ W(N,K)^T + bias. Block 128x128, 4 waves 2x2 (64x64
// each, 4x4 frags). BK=64, double-buffered glds16 staging, XOR chunk swizzle.
template <int ROPE, int OUTMODE, int SCALE>
__global__ __launch_bounds__(256, 2) void gemm_t(
    const short* __restrict__ A, int lda, const short* __restrict__ W, int ldw,
    const float* __restrict__ bias0, const float* __restrict__ bias1,
    int bsplit, int ropestart, void* __restrict__ outp, int ldo, int ocol,
    int K, const int* __restrict__ pos) {
  int tid = threadIdx.x, w = tid >> 6, lane = tid & 63;
  int quad = lane >> 4, l16 = lane & 15;
  int bm = blockIdx.y * 128, bn = blockIdx.x * 128;
  int wm = (w & 1) * 64, wn = (w >> 1) * 64;

  __shared__ short At[2][128 * 64];
  __shared__ short Bt[2][128 * 64];

  int srow[4], soff[4];
#pragma unroll
  for (int j = 0; j < 4; j++) {
    int r = w * 32 + j * 8 + (lane >> 3);
    srow[j] = r;
    soff[j] = ((lane & 7) ^ (r & 7)) << 3;
  }
  const short* Ag = A + (size_t)bm * lda;
  const short* Wg = W + (size_t)bn * ldw;

#pragma unroll
  for (int j = 0; j < 4; j++)
    glds16(Ag + (size_t)srow[j] * lda + soff[j], &At[0][(w * 32 + j * 8) * 64]);
#pragma unroll
  for (int j = 0; j < 4; j++)
    glds16(Wg + (size_t)srow[j] * ldw + soff[j], &Bt[0][(w * 32 + j * 8) * 64]);

  float4v acc[4][4];
  float4v z = {0.f, 0.f, 0.f, 0.f};
#pragma unroll
  for (int mi = 0; mi < 4; mi++)
#pragma unroll
    for (int ni = 0; ni < 4; ni++) acc[mi][ni] = z;

  int nk = K >> 6;
  for (int it = 0; it < nk; it++) {
    __syncthreads();
    if (it + 1 < nk) {
      int kt = (it + 1) << 6, nb = (it + 1) & 1;
#pragma unroll
      for (int j = 0; j < 4; j++)
        glds16(Ag + (size_t)srow[j] * lda + kt + soff[j],
               &At[nb][(w * 32 + j * 8) * 64]);
#pragma unroll
      for (int j = 0; j < 4; j++)
        glds16(Wg + (size_t)srow[j] * ldw + kt + soff[j],
               &Bt[nb][(w * 32 + j * 8) * 64]);
    }
    const short* Ab = At[it & 1];
    const short* Bb = Bt[it & 1];
#pragma unroll
    for (int ks = 0; ks < 2; ks++) {
      short8 af[4], bf[4];
#pragma unroll
      for (int mi = 0; mi < 4; mi++) {
        int row = wm + mi * 16 + l16;
        af[mi] = *(const short8*)&Ab[(row << 6) + ((((ks << 2) + quad) ^ (row & 7)) << 3)];
      }
#pragma unroll
      for (int ni = 0; ni < 4; ni++) {
        int row = wn + ni * 16 + l16;
        bf[ni] = *(const short8*)&Bb[(row << 6) + ((((ks << 2) + quad) ^ (row & 7)) << 3)];
      }
#pragma unroll
      for (int mi = 0; mi < 4; mi++)
#pragma unroll
        for (int ni = 0; ni < 4; ni++)
          acc[mi][ni] = MFMA16(af[mi], bf[ni], acc[mi][ni]);
    }
  }

#pragma unroll
  for (int ni = 0; ni < 4; ni++) {
    int col = bn + wn + ni * 16 + l16;
    float bv = (col < bsplit) ? bias0[col] : bias1[col - bsplit];
    float fr = 0.f;
    bool dorope = ROPE && (col >= ropestart);
    if (dorope) {
      int ri = (col - ropestart) & ~1;
      fr = exp2f((float)ri * (-13.287712379549449f / 768.0f));
    }
#pragma unroll
    for (int mi = 0; mi < 4; mi++) {
      int row0 = bm + wm + mi * 16 + quad * 4;
      if (OUTMODE == 2) {
        int bidx = row0 >> 11, s = row0 & 2047;
        short4v ov;
#pragma unroll
        for (int r = 0; r < 4; r++) ov[r] = f2bf(acc[mi][ni][r] + bv);
        *(short4v*)((short*)outp + ((size_t)(bidx * 1536 + col)) * 2048 + s) = ov;
      } else {
#pragma unroll
        for (int r = 0; r < 4; r++) {
          int row = row0 + r;
          float v = acc[mi][ni][r] + bv;
          if (ROPE) {
            float pv = __shfl_xor(v, 1, 64);
            if (dorope) {
              float ang = (float)pos[row & 2047] * fr;
              float sn, cs;
              __sincosf(ang, &sn, &cs);
              v = (col & 1) ? (pv * sn + v * cs) : (v * cs - pv * sn);
            }
          }
          if (SCALE) v *= 0.12751743f;  // (1/sqrt(128)) * log2(e)
          if (OUTMODE == 1)
            ((float*)outp)[(size_t)row * ldo + ocol + col] = v;
          else
            ((short*)outp)[(size_t)row * ldo + ocol + col] = f2bf(v);
        }
      }
    }
  }
}

// ---------- causal flash attention: 128-q blocks, 32 q/wave, no-max softmax ----
// grid 768 (1-D, global LPT order: rank 0 = the 48 longest q-tiles), 256 thr.
// R6 register shape + max-free softmax (logits pre-scaled by (1/sqrt(128))*log2e
// in the Q GEMM are bounded, softmax = exp2(s) directly). This round:
//  - global longest-first block ordering (fixes 2.5x packing loss seen as
//    OccupancyPercent 9.8%)
//  - v_cvt_pk_bf16_f32 P-packing (~100 VALU/lane/tile saved vs manual RNE)
//  - s_setprio(1) around MFMA clusters (T5)
__global__ __launch_bounds__(256, 2) void mla_attn(const short* __restrict__ Q,
                                                   const short* __restrict__ K,
                                                   const short* __restrict__ Vt,
                                                   short* __restrict__ O) {
  const int ld = 1536, SEQ = 2048;
  int tid = threadIdx.x, w = tid >> 6, lane = tid & 63;
  int quad = lane >> 4, l16 = lane & 15;
  // global LPT mapping: blockIdx 0..47 are the 16th (longest) q-tile of each
  // (b,h); 48..95 the next-longest; ... HW dispatches in index order, so
  // refilled CU slots get progressively shorter blocks.
  int o = (int)blockIdx.x;
  int rank = o / 48;
  int g = o - rank * 48;
  int qt = (15 - rank) * 128;
  int hh = g % 12, b = g / 12;
  int qw = qt + w * 32;

  __shared__ short Kt[2][64 * 128];
  __shared__ short Vl[2][128 * 64];
  __shared__ short Pm[4][32 * 64];
  short* pw = Pm[w];

  int kgo[4], vgo[4];
#pragma unroll
  for (int j = 0; j < 4; j++) {
    int rk = (w * 4 + j) * 4 + (lane >> 4);
    kgo[j] = rk * ld + (((lane & 15) ^ (rk & 7)) << 3);
    int rv = (w * 4 + j) * 8 + (lane >> 3);
    vgo[j] = rv * SEQ + (((lane & 7) ^ (rv & 7)) << 3);
  }
  const short* Kg = K + (size_t)b * SEQ * ld + hh * 128;
  const short* Vg = Vt + (size_t)(b * 12 + hh) * 128 * SEQ;

  short8 qf[2][4];
  {
    const short* Qg = Q + (size_t)(b * SEQ + qw + l16) * ld + hh * 128 + quad * 8;
#pragma unroll
    for (int nf = 0; nf < 2; nf++)
#pragma unroll
      for (int ks = 0; ks < 4; ks++)
        qf[nf][ks] = *(const short8*)(Qg + (size_t)nf * 16 * ld + ks * 32);
  }

  float4v z = {0.f, 0.f, 0.f, 0.f};
  float4v oacc[2][8];
#pragma unroll
  for (int mq = 0; mq < 2; mq++)
#pragma unroll
    for (int df = 0; df < 8; df++) oacc[mq][df] = z;
  float l_i[2] = {0.f, 0.f};  // per-lane partial sums (lane = q column)

#pragma unroll
  for (int j = 0; j < 4; j++) glds16(Kg + kgo[j], &Kt[0][(w * 4 + j) * 512]);
#pragma unroll
  for (int j = 0; j < 4; j++) glds16(Vg + vgo[j], &Vl[0][(w * 4 + j) * 512]);

  int ntiles = (qt >> 6) + 2;
  for (int it = 0; it < ntiles; it++) {
    int kt = it << 6;
    __syncthreads();  // drains prefetch issued one full tile ago
    if (it + 1 < ntiles) {
      int nb = (it + 1) & 1;
      const short* kn = Kg + (size_t)(kt + 64) * ld;
      const short* vn = Vg + (kt + 64);
#pragma unroll
      for (int j = 0; j < 4; j++) glds16(kn + kgo[j], &Kt[nb][(w * 4 + j) * 512]);
#pragma unroll
      for (int j = 0; j < 4; j++) glds16(vn + vgo[j], &Vl[nb][(w * 4 + j) * 512]);
    }
    if (kt > qw + 31) continue;  // wave-uniform: fully-masked tile
    const short* Kb = Kt[it & 1];
    const short* Vb = Vl[it & 1];

    // ---- S^T = K * Q^T : D col = q (l16), row = key (quad*4+r, mf*16) ----
    float4v sf[4][2];
#pragma unroll
    for (int mf = 0; mf < 4; mf++)
#pragma unroll
      for (int nf = 0; nf < 2; nf++) sf[mf][nf] = z;
    __builtin_amdgcn_s_setprio(1);
#pragma unroll
    for (int ks = 0; ks < 4; ks++)
#pragma unroll
      for (int mf = 0; mf < 4; mf++) {
        int row = mf * 16 + l16;
        short8 a = *(const short8*)&Kb[(row << 7) + (((ks * 4 + quad) ^ (row & 7)) << 3)];
#pragma unroll
        for (int nf = 0; nf < 2; nf++) sf[mf][nf] = MFMA16(a, qf[nf][ks], sf[mf][nf]);
      }
    __builtin_amdgcn_s_setprio(0);
    // ---- causal mask: only tiles crossing the diagonal ----
    if (kt + 63 > qw) {
#pragma unroll
      for (int mf = 0; mf < 4; mf++) {
        int key = kt + mf * 16 + quad * 4;
#pragma unroll
        for (int nf = 0; nf < 2; nf++) {
          int q = qw + nf * 16 + l16;
#pragma unroll
          for (int r = 0; r < 4; r++)
            if (key + r > q) sf[mf][nf][r] = -3e38f;
        }
      }
    }
    // ---- softmax: exp2 only (no max tracking), per-lane partial l ----
#pragma unroll
    for (int nf = 0; nf < 2; nf++) {
      float ps = 0.f;
#pragma unroll
      for (int mf = 0; mf < 4; mf++)
#pragma unroll
        for (int r = 0; r < 4; r++) {
          float e = exp2f(sf[mf][nf][r]);
          sf[mf][nf][r] = e;
          ps += e;
        }
      l_i[nf] += ps;
      // ---- P pack -> per-wave LDS (swizzled), packed bf16 converts ----
#pragma unroll
      for (int mf = 0; mf < 4; mf++) {
        int2v pk;
        pk[0] = cvtpk(sf[mf][nf][0], sf[mf][nf][1]);
        pk[1] = cvtpk(sf[mf][nf][2], sf[mf][nf][3]);
        int p = (mf * 2 + (quad >> 1)) ^ (l16 & 7);
        *(int2v*)&pw[((nf * 16 + l16) << 6) + (p << 3) + ((quad & 1) << 2)] = pk;
      }
    }
    // ---- O += P * V ----
    __builtin_amdgcn_s_setprio(1);
#pragma unroll
    for (int t = 0; t < 2; t++) {
      short8 pf[2];
#pragma unroll
      for (int mq = 0; mq < 2; mq++)
        pf[mq] = *(const short8*)&pw[((mq * 16 + l16) << 6) +
                                     ((((t << 2) + quad) ^ (l16 & 7)) << 3)];
#pragma unroll
      for (int df = 0; df < 8; df++) {
        int vr = df * 16 + l16;
        short8 vf = *(const short8*)&Vb[(vr << 6) + ((((t << 2) + quad) ^ (vr & 7)) << 3)];
#pragma unroll
        for (int mq = 0; mq < 2; mq++) oacc[mq][df] = MFMA16(pf[mq], vf, oacc[mq][df]);
      }
    }
    __builtin_amdgcn_s_setprio(0);
  }

  // ---- epilogue: reduce l across quads, scale, store ----
  short* Og = O + (size_t)(b * SEQ + qw) * ld + hh * 128;
#pragma unroll
  for (int mq = 0; mq < 2; mq++) {
    float l = l_i[mq];
    l += __shfl_xor(l, 16, 64);
    l += __shfl_xor(l, 32, 64);
    float linv = 1.0f / l;
    float lb[4];
#pragma unroll
    for (int r = 0; r < 4; r++) lb[r] = __shfl(linv, (quad << 2) + r, 64);
#pragma unroll
    for (int df = 0; df < 8; df++)
#pragma unroll
      for (int r = 0; r < 4; r++)
        Og[(size_t)(mq * 16 + (quad << 2) + r) * ld + df * 16 + l16] =
            f2bf(oacc[mq][df][r] * lb[r]);
  }
}

// ---------- launcher ----------
extern "C" void kernel_launch(void* const* d_in, const int* in_sizes, int n_in,
                              void* d_out, int out_size, void* d_ws, size_t ws_size,
                              hipStream_t stream) {
  const int S = 2048, DM = 768, DL = 128, HD = 1536;
  const int M = 4 * S;  // 8192
  const int BIG = 1 << 28;

  const float* x = (const float*)d_in[0];
  const int* pos = (const int*)d_in[1];
  const float* W_dkv = (const float*)d_in[2];
  const float* b_dkv = (const float*)d_in[3];
  const float* W_dq = (const float*)d_in[4];
  const float* b_dq = (const float*)d_in[5];
  const float* W_uk_nope = (const float*)d_in[6];
  const float* b_uk_nope = (const float*)d_in[7];
  const float* W_uv = (const float*)d_in[8];
  const float* b_uv = (const float*)d_in[9];
  const float* W_uq_nope = (const float*)d_in[10];
  const float* b_uq_nope = (const float*)d_in[11];
  const float* W_uq_rope = (const float*)d_in[12];
  const float* b_uq_rope = (const float*)d_in[13];
  const float* W_uk_rope = (const float*)d_in[14];
  const float* b_uk_rope = (const float*)d_in[15];
  const float* W_o = (const float*)d_in[16];
  const float* b_o = (const float*)d_in[17];

  char* p = (char*)d_ws;
  size_t off = 0;
  auto take = [&](size_t nelem) -> short* {
    short* r = (short*)(p + off);
    off += (nelem * 2 + 255) & ~(size_t)255;
    return r;
  };
  short* xb = take((size_t)M * DM);
  short* Wdq = take(DL * DM);      // [Wdq; Wdkv] contiguous
  short* Wdkv = take(DL * DM);
  short* Wuqnope = take(768 * DL); // [Wuqnope; Wuqrope] contiguous
  short* Wuqrope = take(768 * DL);
  short* Wuknope = take(768 * DL);
  short* Wuv = take(1536 * DL);
  short* Wukrope = take(768 * DM);
  short* Wo = take(768 * 1536);
  short* Cm = take((size_t)M * 256);  // [C_q | C_kv]
  short* Qm = take((size_t)M * HD);
  short* Km = take((size_t)M * HD);
  short* Vtm = take((size_t)M * HD);  // V^T: [b][h*128+d][s]
  short* Om = take((size_t)M * HD);
  if (off > ws_size) return;

  CastArgs ca;
  const float* srcs[9] = {x, W_dq, W_dkv, W_uq_nope, W_uq_rope, W_uk_nope, W_uv, W_uk_rope, W_o};
  short* dsts[9] = {xb, Wdq, Wdkv, Wuqnope, Wuqrope, Wuknope, Wuv, Wukrope, Wo};
  int ns[9] = {M * DM, DL * DM, DL * DM, 768 * DL, 768 * DL, 768 * DL, 1536 * DL, 768 * DM, 768 * 1536};
  ca.start[0] = 0;
  for (int i = 0; i < 9; i++) {
    ca.seg[i].src = srcs[i];
    ca.seg[i].dst = dsts[i];
    ca.seg[i].n4 = ns[i] / 4;
    ca.start[i + 1] = ca.start[i] + (ca.seg[i].n4 + 255) / 256;
  }
  castk<<<dim3(ca.start[9]), dim3(256), 0, stream>>>(ca);

  // C = [C_q | C_kv] = x @ [Wdq;Wdkv]^T   (N=256, K=768)
  gemm_t<0, 0, 0><<<dim3(2, M / 128), dim3(256), 0, stream>>>(
      xb, DM, Wdq, DM, b_dq, b_dkv, 128, 0, Cm, 256, 0, DM, pos);
  // Q = [q_nope | rope(q_rope)] (N=1536, K=128), scale folded
  gemm_t<1, 0, 1><<<dim3(12, M / 128), dim3(256), 0, stream>>>(
      Cm, 256, Wuqnope, DL, b_uq_nope, b_uq_rope, 768, 768, Qm, HD, 0, DL, pos);
  // k_nope (N=768, K=128)
  gemm_t<0, 0, 0><<<dim3(6, M / 128), dim3(256), 0, stream>>>(
      Cm + 128, 256, Wuknope, DL, b_uk_nope, b_uk_nope, BIG, 0, Km, HD, 0, DL, pos);
  // rope(k_rope) from x (N=768, K=768)
  gemm_t<1, 0, 0><<<dim3(6, M / 128), dim3(256), 0, stream>>>(
      xb, DM, Wukrope, DM, b_uk_rope, b_uk_rope, BIG, 0, Km, HD, 768, DM, pos);
  // V -> V^T (N=1536, K=128)
  gemm_t<0, 2, 0><<<dim3(12, M / 128), dim3(256), 0, stream>>>(
      Cm + 128, 256, Wuv, DL, b_uv, b_uv, BIG, 0, Vtm, 0, 0, DL, pos);
  // attention: 768 blocks, global longest-first (LPT) order
  mla_attn<<<dim3(768), dim3(256), 0, stream>>>(Qm, Km, Vtm, Om);
  // out = O @ W_o^T + b_o (N=768, K=1536, fp32)
  gemm_t<0, 1, 0><<<dim3(6, M / 128), dim3(256), 0, stream>>>(
      Om, HD, Wo, HD, b_o, b_o, BIG, 0, d_out, 768, 0, HD, pos);
}

// Round 2
// 311.037 us; speedup vs baseline: 1.2906x; 1.0498x over previous
//
#include <hip/hip_runtime.h>

// ---------- types ----------
typedef __attribute__((ext_vector_type(8))) short short8;   // 8 x bf16
typedef __attribute__((ext_vector_type(4))) short short4v;  // 4 x bf16
typedef __attribute__((ext_vector_type(2))) int int2v;
typedef __attribute__((ext_vector_type(4))) float float4v;

#define MFMA16(a, b, c) __builtin_amdgcn_mfma_f32_16x16x32_bf16((a), (b), (c), 0, 0, 0)

__device__ __forceinline__ short f2bf(float f) {  // RNE fp32 -> bf16
  unsigned u = __float_as_uint(f);
  u += 0x7fffu + ((u >> 16) & 1u);
  return (short)(u >> 16);
}

// packed fp32x2 -> bf16x2 (RNE) in one VALU op
__device__ __forceinline__ int cvtpk(float a, float b) {
  int r;
  asm("v_cvt_pk_bf16_f32 %0, %1, %2" : "=v"(r) : "v"(a), "v"(b));
  return r;
}

// async global->LDS, 16B per lane; LDS dest = wave-uniform base + lane*16
__device__ __forceinline__ void glds16(const short* g, short* l) {
  __builtin_amdgcn_global_load_lds(
      (const __attribute__((address_space(1))) void*)g,
      (__attribute__((address_space(3))) void*)l, 16, 0, 0);
}

// ---------- fused fp32 -> bf16 cast (all 9 tensors, one launch) ----------
struct CastSeg { const float* src; short* dst; int n4; };
struct CastArgs { CastSeg seg[9]; int start[10]; };

__global__ __launch_bounds__(256) void castk(CastArgs a) {
  int blk = blockIdx.x;
  int si = 0;
#pragma unroll
  for (int i = 1; i < 9; i++) si += (blk >= a.start[i]);
  int i = (blk - a.start[si]) * 256 + threadIdx.x;
  if (i >= a.seg[si].n4) return;
  float4v f = ((const float4v*)a.seg[si].src)[i];
  short4v o;
  o[0] = f2bf(f[0]); o[1] = f2bf(f[1]); o[2] = f2bf(f[2]); o[3] = f2bf(f[3]);
  ((short4v*)a.seg[si].dst)[i] = o;
}

// ---------- segmented runtime-flag MFMA GEMM (m97 structure) ----------
// out[m, ocol+n] = A(M,K) @ W(N,K)^T + bias. Block 128x128, 4 waves 2x2.
// BK=64, glds16 staging, XOR chunk swizzle. Segments let independent GEMMs
// share one launch (fill + fewer gaps). K==128 fast path: stage both K-halves
// upfront, single barrier.
// flags: 1=ROPE epilogue, 2=SCALE (qk scale), 4=V^T out, 8=fp32 out
struct GSeg {
  const short* A;
  const short* W;
  const float* bias0;
  const float* bias1;
  void* outp;
  int lda, ldw, bsplit, ropestart, ldo, ocol, K, flags;
};
struct GArgs { GSeg s[3]; int start[4]; };

__global__ __launch_bounds__(256, 2) void gemm_rt(GArgs ga, const int* __restrict__ pos) {
  int bx = blockIdx.x;
  int si = (bx >= ga.start[1]) + (bx >= ga.start[2]);
  const GSeg sg = ga.s[si];
  int tid = threadIdx.x, w = tid >> 6, lane = tid & 63;
  int quad = lane >> 4, l16 = lane & 15;
  int bm = blockIdx.y * 128, bn = (bx - ga.start[si]) * 128;
  int wm = (w & 1) * 64, wn = (w >> 1) * 64;
  int lda = sg.lda, ldw = sg.ldw;

  __shared__ short At[2][128 * 64];
  __shared__ short Bt[2][128 * 64];

  int srow[4], soff[4];
#pragma unroll
  for (int j = 0; j < 4; j++) {
    int r = w * 32 + j * 8 + (lane >> 3);
    srow[j] = r;
    soff[j] = ((lane & 7) ^ (r & 7)) << 3;
  }
  const short* Ag = sg.A + (size_t)bm * lda;
  const short* Wg = sg.W + (size_t)bn * ldw;

  float4v acc[4][4];
  float4v z = {0.f, 0.f, 0.f, 0.f};
#pragma unroll
  for (int mi = 0; mi < 4; mi++)
#pragma unroll
    for (int ni = 0; ni < 4; ni++) acc[mi][ni] = z;

  auto comp = [&](const short* Ab, const short* Bb) {
#pragma unroll
    for (int ks = 0; ks < 2; ks++) {
      short8 af[4], bf[4];
#pragma unroll
      for (int mi = 0; mi < 4; mi++) {
        int row = wm + mi * 16 + l16;
        af[mi] = *(const short8*)&Ab[(row << 6) + ((((ks << 2) + quad) ^ (row & 7)) << 3)];
      }
#pragma unroll
      for (int ni = 0; ni < 4; ni++) {
        int row = wn + ni * 16 + l16;
        bf[ni] = *(const short8*)&Bb[(row << 6) + ((((ks << 2) + quad) ^ (row & 7)) << 3)];
      }
#pragma unroll
      for (int mi = 0; mi < 4; mi++)
#pragma unroll
        for (int ni = 0; ni < 4; ni++)
          acc[mi][ni] = MFMA16(af[mi], bf[ni], acc[mi][ni]);
    }
  };

  int nk = sg.K >> 6;
  if (nk == 2) {
    // thin-K fast path: stage K=128 entirely, one barrier, 128 MFMAs straight
#pragma unroll
    for (int j = 0; j < 4; j++) {
      glds16(Ag + (size_t)srow[j] * lda + soff[j], &At[0][(w * 32 + j * 8) * 64]);
      glds16(Ag + (size_t)srow[j] * lda + 64 + soff[j], &At[1][(w * 32 + j * 8) * 64]);
      glds16(Wg + (size_t)srow[j] * ldw + soff[j], &Bt[0][(w * 32 + j * 8) * 64]);
      glds16(Wg + (size_t)srow[j] * ldw + 64 + soff[j], &Bt[1][(w * 32 + j * 8) * 64]);
    }
    __syncthreads();
    comp(At[0], Bt[0]);
    comp(At[1], Bt[1]);
  } else {
#pragma unroll
    for (int j = 0; j < 4; j++)
      glds16(Ag + (size_t)srow[j] * lda + soff[j], &At[0][(w * 32 + j * 8) * 64]);
#pragma unroll
    for (int j = 0; j < 4; j++)
      glds16(Wg + (size_t)srow[j] * ldw + soff[j], &Bt[0][(w * 32 + j * 8) * 64]);
    for (int it = 0; it < nk; it++) {
      __syncthreads();
      if (it + 1 < nk) {
        int kt = (it + 1) << 6, nb = (it + 1) & 1;
#pragma unroll
        for (int j = 0; j < 4; j++)
          glds16(Ag + (size_t)srow[j] * lda + kt + soff[j],
                 &At[nb][(w * 32 + j * 8) * 64]);
#pragma unroll
        for (int j = 0; j < 4; j++)
          glds16(Wg + (size_t)srow[j] * ldw + kt + soff[j],
                 &Bt[nb][(w * 32 + j * 8) * 64]);
      }
      comp(At[it & 1], Bt[it & 1]);
    }
  }

  // ---- epilogue (runtime flags; all branches block-uniform) ----
  bool ropeF = sg.flags & 1, scaleF = sg.flags & 2;
  bool vtF = sg.flags & 4, f32F = sg.flags & 8;
#pragma unroll
  for (int ni = 0; ni < 4; ni++) {
    int col = bn + wn + ni * 16 + l16;
    float bv = (col < sg.bsplit) ? sg.bias0[col] : sg.bias1[col - sg.bsplit];
    float fr = 0.f;
    bool dorope = ropeF && (col >= sg.ropestart);
    if (dorope) {
      int ri = (col - sg.ropestart) & ~1;
      fr = exp2f((float)ri * (-13.287712379549449f / 768.0f));
    }
#pragma unroll
    for (int mi = 0; mi < 4; mi++) {
      int row0 = bm + wm + mi * 16 + quad * 4;
      if (vtF) {
        int bidx = row0 >> 11, s = row0 & 2047;
        short4v ov;
#pragma unroll
        for (int r = 0; r < 4; r++) ov[r] = f2bf(acc[mi][ni][r] + bv);
        *(short4v*)((short*)sg.outp + ((size_t)(bidx * 1536 + col)) * 2048 + s) = ov;
      } else {
#pragma unroll
        for (int r = 0; r < 4; r++) {
          int row = row0 + r;
          float v = acc[mi][ni][r] + bv;
          if (ropeF) {
            float pv = __shfl_xor(v, 1, 64);
            if (dorope) {
              float ang = (float)pos[row & 2047] * fr;
              float sn, cs;
              __sincosf(ang, &sn, &cs);
              v = (col & 1) ? (pv * sn + v * cs) : (v * cs - pv * sn);
            }
          }
          if (scaleF) v *= 0.12751743f;  // (1/sqrt(128)) * log2(e)
          if (f32F)
            ((float*)sg.outp)[(size_t)row * sg.ldo + sg.ocol + col] = v;
          else
            ((short*)sg.outp)[(size_t)row * sg.ldo + sg.ocol + col] = f2bf(v);
        }
      }
    }
  }
}

// ---------- causal flash attention: 128-q blocks, 32 q/wave, no-max softmax ----
// grid 768 (1-D, global LPT order), 256 thr. This round: (a) all LDS byte
// offsets precomputed once, tile loop unrolled x2 with literal buffer index so
// ds addresses are reg+imm (no per-tile address VALU); (b) QK accumulator
// seeded by k=0 MFMA with a shared zero vector (kills 32 v_movs/tile).
__global__ __launch_bounds__(256, 2) void mla_attn(const short* __restrict__ Q,
                                                   const short* __restrict__ K,
                                                   const short* __restrict__ Vt,
                                                   short* __restrict__ O) {
  const int ld = 1536, SEQ = 2048;
  int tid = threadIdx.x, w = tid >> 6, lane = tid & 63;
  int quad = lane >> 4, l16 = lane & 15;
  int o = (int)blockIdx.x;
  int rank = o / 48;
  int g = o - rank * 48;
  int qt = (15 - rank) * 128;
  int hh = g % 12, b = g / 12;
  int qw = qt + w * 32;

  __shared__ short Kt[2][64 * 128];
  __shared__ short Vl[2][128 * 64];
  __shared__ short Pm[4][32 * 64];
  char* pwB = (char*)Pm[w];

  int kgo[4], vgo[4];
#pragma unroll
  for (int j = 0; j < 4; j++) {
    int rk = (w * 4 + j) * 4 + (lane >> 4);
    kgo[j] = rk * ld + (((lane & 15) ^ (rk & 7)) << 3);
    int rv = (w * 4 + j) * 8 + (lane >> 3);
    vgo[j] = rv * SEQ + (((lane & 7) ^ (rv & 7)) << 3);
  }
  const short* Kg = K + (size_t)b * SEQ * ld + hh * 128;
  const short* Vg = Vt + (size_t)(b * 12 + hh) * 128 * SEQ;

  short8 qf[2][4];
  {
    const short* Qg = Q + (size_t)(b * SEQ + qw + l16) * ld + hh * 128 + quad * 8;
#pragma unroll
    for (int nf = 0; nf < 2; nf++)
#pragma unroll
      for (int ks = 0; ks < 4; ks++)
        qf[nf][ks] = *(const short8*)(Qg + (size_t)nf * 16 * ld + ks * 32);
  }

  // ---- loop-invariant LDS byte offsets ----
  int koff[4][4], voff[2][8], pfo[2][2], pwo[2][4];
#pragma unroll
  for (int ks = 0; ks < 4; ks++)
#pragma unroll
    for (int mf = 0; mf < 4; mf++) {
      int row = mf * 16 + l16;
      koff[ks][mf] = row * 256 + ((((ks << 2) + quad) ^ (row & 7)) << 4);
    }
#pragma unroll
  for (int t = 0; t < 2; t++) {
#pragma unroll
    for (int df = 0; df < 8; df++) {
      int vr = df * 16 + l16;
      voff[t][df] = vr * 128 + ((((t << 2) + quad) ^ (vr & 7)) << 4);
    }
#pragma unroll
    for (int mq = 0; mq < 2; mq++)
      pfo[t][mq] = (mq * 16 + l16) * 128 + ((((t << 2) + quad) ^ (l16 & 7)) << 4);
#pragma unroll
    for (int mf = 0; mf < 4; mf++) {
      int p = (mf * 2 + (quad >> 1)) ^ (l16 & 7);
      pwo[t][mf] = (t * 16 + l16) * 128 + (p << 4) + ((quad & 1) << 3);
    }
  }

  float4v z = {0.f, 0.f, 0.f, 0.f};
  float4v oacc[2][8];
#pragma unroll
  for (int mq = 0; mq < 2; mq++)
#pragma unroll
    for (int df = 0; df < 8; df++) oacc[mq][df] = z;
  float l_i[2] = {0.f, 0.f};

#pragma unroll
  for (int j = 0; j < 4; j++) glds16(Kg + kgo[j], &Kt[0][(w * 4 + j) * 512]);
#pragma unroll
  for (int j = 0; j < 4; j++) glds16(Vg + vgo[j], &Vl[0][(w * 4 + j) * 512]);

  int ntiles = (qt >> 6) + 2;  // always even

#define ATTN_TILE(IT, NB, NB1)                                                 \
  do {                                                                         \
    int kt = (IT) << 6;                                                        \
    __syncthreads();                                                           \
    if ((IT) + 1 < ntiles) {                                                   \
      const short* kn = Kg + (size_t)(kt + 64) * ld;                           \
      const short* vn = Vg + (kt + 64);                                        \
      _Pragma("unroll") for (int j = 0; j < 4; j++)                            \
          glds16(kn + kgo[j], &Kt[NB1][(w * 4 + j) * 512]);                    \
      _Pragma("unroll") for (int j = 0; j < 4; j++)                            \
          glds16(vn + vgo[j], &Vl[NB1][(w * 4 + j) * 512]);                    \
    }                                                                          \
    if (kt <= qw + 31) {                                                       \
      const char* Kb = (const char*)Kt[NB];                                    \
      const char* Vb = (const char*)Vl[NB];                                    \
      float4v sf[4][2];                                                        \
      __builtin_amdgcn_s_setprio(1);                                           \
      _Pragma("unroll") for (int mf = 0; mf < 4; mf++) {                       \
        short8 a = *(const short8*)(Kb + koff[0][mf]);                         \
        sf[mf][0] = MFMA16(a, qf[0][0], z);                                    \
        sf[mf][1] = MFMA16(a, qf[1][0], z);                                    \
      }                                                                        \
      _Pragma("unroll") for (int ks = 1; ks < 4; ks++) {                       \
        _Pragma("unroll") for (int mf = 0; mf < 4; mf++) {                     \
          short8 a = *(const short8*)(Kb + koff[ks][mf]);                      \
          sf[mf][0] = MFMA16(a, qf[0][ks], sf[mf][0]);                         \
          sf[mf][1] = MFMA16(a, qf[1][ks], sf[mf][1]);                         \
        }                                                                      \
      }                                                                        \
      __builtin_amdgcn_s_setprio(0);                                           \
      if (kt + 63 > qw) {                                                      \
        _Pragma("unroll") for (int mf = 0; mf < 4; mf++) {                     \
          int key = kt + mf * 16 + quad * 4;                                   \
          _Pragma("unroll") for (int nf = 0; nf < 2; nf++) {                   \
            int q = qw + nf * 16 + l16;                                        \
            _Pragma("unroll") for (int r = 0; r < 4; r++)                      \
                if (key + r > q) sf[mf][nf][r] = -3e38f;                       \
          }                                                                    \
        }                                                                      \
      }                                                                        \
      _Pragma("unroll") for (int nf = 0; nf < 2; nf++) {                       \
        float ps = 0.f;                                                        \
        _Pragma("unroll") for (int mf = 0; mf < 4; mf++)                       \
            _Pragma("unroll") for (int r = 0; r < 4; r++) {                    \
          float e = exp2f(sf[mf][nf][r]);                                      \
          sf[mf][nf][r] = e;                                                   \
          ps += e;                                                             \
        }                                                                      \
        l_i[nf] += ps;                                                         \
        _Pragma("unroll") for (int mf = 0; mf < 4; mf++) {                     \
          int2v pk;                                                            \
          pk[0] = cvtpk(sf[mf][nf][0], sf[mf][nf][1]);                         \
          pk[1] = cvtpk(sf[mf][nf][2], sf[mf][nf][3]);                         \
          *(int2v*)(pwB + pwo[nf][mf]) = pk;                                   \
        }                                                                      \
      }                                                                        \
      __builtin_amdgcn_s_setprio(1);                                           \
      _Pragma("unroll") for (int t = 0; t < 2; t++) {                          \
        short8 pf0 = *(const short8*)(pwB + pfo[t][0]);                        \
        short8 pf1 = *(const short8*)(pwB + pfo[t][1]);                        \
        _Pragma("unroll") for (int df = 0; df < 8; df++) {                     \
          short8 vf = *(const short8*)(Vb + voff[t][df]);                      \
          oacc[0][df] = MFMA16(pf0, vf, oacc[0][df]);                          \
          oacc[1][df] = MFMA16(pf1, vf, oacc[1][df]);                          \
        }                                                                      \
      }                                                                        \
      __builtin_amdgcn_s_setprio(0);                                           \
    }                                                                          \
  } while (0)

  for (int it = 0; it < ntiles; it += 2) {
    ATTN_TILE(it, 0, 1);
    ATTN_TILE(it + 1, 1, 0);
  }
#undef ATTN_TILE

  // ---- epilogue: reduce l across quads, scale, store ----
  short* Og = O + (size_t)(b * SEQ + qw) * ld + hh * 128;
#pragma unroll
  for (int mq = 0; mq < 2; mq++) {
    float l = l_i[mq];
    l += __shfl_xor(l, 16, 64);
    l += __shfl_xor(l, 32, 64);
    float linv = 1.0f / l;
    float lb[4];
#pragma unroll
    for (int r = 0; r < 4; r++) lb[r] = __shfl(linv, (quad << 2) + r, 64);
#pragma unroll
    for (int df = 0; df < 8; df++)
#pragma unroll
      for (int r = 0; r < 4; r++)
        Og[(size_t)(mq * 16 + (quad << 2) + r) * ld + df * 16 + l16] =
            f2bf(oacc[mq][df][r] * lb[r]);
  }
}

// ---------- launcher ----------
extern "C" void kernel_launch(void* const* d_in, const int* in_sizes, int n_in,
                              void* d_out, int out_size, void* d_ws, size_t ws_size,
                              hipStream_t stream) {
  const int S = 2048, DM = 768, DL = 128, HD = 1536;
  const int M = 4 * S;  // 8192
  const int BIG = 1 << 28;

  const float* x = (const float*)d_in[0];
  const int* pos = (const int*)d_in[1];
  const float* W_dkv = (const float*)d_in[2];
  const float* b_dkv = (const float*)d_in[3];
  const float* W_dq = (const float*)d_in[4];
  const float* b_dq = (const float*)d_in[5];
  const float* W_uk_nope = (const float*)d_in[6];
  const float* b_uk_nope = (const float*)d_in[7];
  const float* W_uv = (const float*)d_in[8];
  const float* b_uv = (const float*)d_in[9];
  const float* W_uq_nope = (const float*)d_in[10];
  const float* b_uq_nope = (const float*)d_in[11];
  const float* W_uq_rope = (const float*)d_in[12];
  const float* b_uq_rope = (const float*)d_in[13];
  const float* W_uk_rope = (const float*)d_in[14];
  const float* b_uk_rope = (const float*)d_in[15];
  const float* W_o = (const float*)d_in[16];
  const float* b_o = (const float*)d_in[17];

  char* p = (char*)d_ws;
  size_t off = 0;
  auto take = [&](size_t nelem) -> short* {
    short* r = (short*)(p + off);
    off += (nelem * 2 + 255) & ~(size_t)255;
    return r;
  };
  short* xb = take((size_t)M * DM);
  short* Wdq = take(DL * DM);
  short* Wdkv = take(DL * DM);
  short* Wuqnope = take(768 * DL);
  short* Wuqrope = take(768 * DL);
  short* Wuknope = take(768 * DL);
  short* Wuv = take(1536 * DL);
  short* Wukrope = take(768 * DM);
  short* Wo = take(768 * 1536);
  short* Cm = take((size_t)M * 256);  // [C_q | C_kv]
  short* Qm = take((size_t)M * HD);
  short* Km = take((size_t)M * HD);
  short* Vtm = take((size_t)M * HD);  // V^T: [b][h*128+d][s]
  short* Om = take((size_t)M * HD);
  if (off > ws_size) return;

  CastArgs ca;
  const float* srcs[9] = {x, W_dq, W_dkv, W_uq_nope, W_uq_rope, W_uk_nope, W_uv, W_uk_rope, W_o};
  short* dsts[9] = {xb, Wdq, Wdkv, Wuqnope, Wuqrope, Wuknope, Wuv, Wukrope, Wo};
  int ns[9] = {M * DM, DL * DM, DL * DM, 768 * DL, 768 * DL, 768 * DL, 1536 * DL, 768 * DM, 768 * 1536};
  ca.start[0] = 0;
  for (int i = 0; i < 9; i++) {
    ca.seg[i].src = srcs[i];
    ca.seg[i].dst = dsts[i];
    ca.seg[i].n4 = ns[i] / 4;
    ca.start[i + 1] = ca.start[i] + (ca.seg[i].n4 + 255) / 256;
  }
  castk<<<dim3(ca.start[9]), dim3(256), 0, stream>>>(ca);

  // ---- launch 1: C (N=256,K=768) || rope(k_rope) (N=768,K=768) ----
  GArgs g1;
  // seg0: C = [C_q | C_kv] = x @ [Wdq;Wdkv]^T
  g1.s[0].A = xb;   g1.s[0].W = Wdq;      g1.s[0].bias0 = b_dq;      g1.s[0].bias1 = b_dkv;
  g1.s[0].outp = Cm; g1.s[0].lda = DM; g1.s[0].ldw = DM; g1.s[0].bsplit = 128;
  g1.s[0].ropestart = 0; g1.s[0].ldo = 256; g1.s[0].ocol = 0; g1.s[0].K = DM; g1.s[0].flags = 0;
  // seg1: k_rope from x, rope'd, into Km cols 768..1535
  g1.s[1].A = xb;   g1.s[1].W = Wukrope;  g1.s[1].bias0 = b_uk_rope; g1.s[1].bias1 = b_uk_rope;
  g1.s[1].outp = Km; g1.s[1].lda = DM; g1.s[1].ldw = DM; g1.s[1].bsplit = BIG;
  g1.s[1].ropestart = 0; g1.s[1].ldo = HD; g1.s[1].ocol = 768; g1.s[1].K = DM; g1.s[1].flags = 1;
  g1.s[2] = g1.s[1];
  g1.start[0] = 0; g1.start[1] = 2; g1.start[2] = 8; g1.start[3] = 8;
  gemm_rt<<<dim3(8, M / 128), dim3(256), 0, stream>>>(g1, pos);

  // ---- launch 2: Q (N=1536) || k_nope (N=768) || V^T (N=1536), all K=128 ----
  GArgs g2;
  // seg0: Q = [q_nope | rope(q_rope)], scale folded
  g2.s[0].A = Cm;   g2.s[0].W = Wuqnope;  g2.s[0].bias0 = b_uq_nope; g2.s[0].bias1 = b_uq_rope;
  g2.s[0].outp = Qm; g2.s[0].lda = 256; g2.s[0].ldw = DL; g2.s[0].bsplit = 768;
  g2.s[0].ropestart = 768; g2.s[0].ldo = HD; g2.s[0].ocol = 0; g2.s[0].K = DL; g2.s[0].flags = 1 | 2;
  // seg1: k_nope into Km cols 0..767
  g2.s[1].A = Cm + 128; g2.s[1].W = Wuknope; g2.s[1].bias0 = b_uk_nope; g2.s[1].bias1 = b_uk_nope;
  g2.s[1].outp = Km; g2.s[1].lda = 256; g2.s[1].ldw = DL; g2.s[1].bsplit = BIG;
  g2.s[1].ropestart = 0; g2.s[1].ldo = HD; g2.s[1].ocol = 0; g2.s[1].K = DL; g2.s[1].flags = 0;
  // seg2: V -> V^T
  g2.s[2].A = Cm + 128; g2.s[2].W = Wuv;   g2.s[2].bias0 = b_uv;      g2.s[2].bias1 = b_uv;
  g2.s[2].outp = Vtm; g2.s[2].lda = 256; g2.s[2].ldw = DL; g2.s[2].bsplit = BIG;
  g2.s[2].ropestart = 0; g2.s[2].ldo = 0; g2.s[2].ocol = 0; g2.s[2].K = DL; g2.s[2].flags = 4;
  g2.start[0] = 0; g2.start[1] = 12; g2.start[2] = 18; g2.start[3] = 30;
  gemm_rt<<<dim3(30, M / 128), dim3(256), 0, stream>>>(g2, pos);

  // ---- attention: 768 blocks, global longest-first (LPT) order ----
  mla_attn<<<dim3(768), dim3(256), 0, stream>>>(Qm, Km, Vtm, Om);

  // ---- launch 3: out = O @ W_o^T + b_o (N=768, K=1536, fp32 out) ----
  GArgs g3;
  g3.s[0].A = Om;   g3.s[0].W = Wo;       g3.s[0].bias0 = b_o;       g3.s[0].bias1 = b_o;
  g3.s[0].outp = d_out; g3.s[0].lda = HD; g3.s[0].ldw = HD; g3.s[0].bsplit = BIG;
  g3.s[0].ropestart = 0; g3.s[0].ldo = 768; g3.s[0].ocol = 0; g3.s[0].K = HD; g3.s[0].flags = 8;
  g3.s[1] = g3.s[0];
  g3.s[2] = g3.s[0];
  g3.start[0] = 0; g3.start[1] = 6; g3.start[2] = 6; g3.start[3] = 6;
  gemm_rt<<<dim3(6, M / 128), dim3(256), 0, stream>>>(g3, pos);
}

// Round 3
// 304.258 us; speedup vs baseline: 1.3193x; 1.0223x over previous
//
#include <hip/hip_runtime.h>

// ---------- types ----------
typedef __attribute__((ext_vector_type(8))) short short8;   // 8 x bf16
typedef __attribute__((ext_vector_type(4))) short short4v;  // 4 x bf16
typedef __attribute__((ext_vector_type(2))) int int2v;
typedef __attribute__((ext_vector_type(4))) float float4v;

#define MFMA16(a, b, c) __builtin_amdgcn_mfma_f32_16x16x32_bf16((a), (b), (c), 0, 0, 0)

__device__ __forceinline__ short f2bf(float f) {  // RNE fp32 -> bf16
  unsigned u = __float_as_uint(f);
  u += 0x7fffu + ((u >> 16) & 1u);
  return (short)(u >> 16);
}

// packed fp32x2 -> bf16x2 (RNE) in one VALU op
__device__ __forceinline__ int cvtpk(float a, float b) {
  int r;
  asm("v_cvt_pk_bf16_f32 %0, %1, %2" : "=v"(r) : "v"(a), "v"(b));
  return r;
}

// async global->LDS, 16B per lane; LDS dest = wave-uniform base + lane*16
__device__ __forceinline__ void glds16(const short* g, short* l) {
  __builtin_amdgcn_global_load_lds(
      (const __attribute__((address_space(1))) void*)g,
      (__attribute__((address_space(3))) void*)l, 16, 0, 0);
}

// ---------- fused fp32 -> bf16 cast (all 9 tensors, one launch) ----------
struct CastSeg { const float* src; short* dst; int n4; };
struct CastArgs { CastSeg seg[9]; int start[10]; };

__global__ __launch_bounds__(256) void castk(CastArgs a) {
  int blk = blockIdx.x;
  int si = 0;
#pragma unroll
  for (int i = 1; i < 9; i++) si += (blk >= a.start[i]);
  int i = (blk - a.start[si]) * 256 + threadIdx.x;
  if (i >= a.seg[si].n4) return;
  float4v f = ((const float4v*)a.seg[si].src)[i];
  short4v o;
  o[0] = f2bf(f[0]); o[1] = f2bf(f[1]); o[2] = f2bf(f[2]); o[3] = f2bf(f[3]);
  ((short4v*)a.seg[si].dst)[i] = o;
}

// ---------- segmented runtime-flag MFMA GEMM (m97 structure) ----------
// out[m, ocol+n] = A(M,K) @ W(N,K)^T + bias. Block 128x128, 4 waves 2x2.
// BK=64, glds16 staging, XOR chunk swizzle.
// Grid: blockIdx.x = m-tile (fastest) -> flat%8 == m-tile%8 -> each XCD owns
// a set of m-rows; row-operand (x/Cm/Om) is HBM-fetched once, L2-hit after.
// blockIdx.y = bn-unit, segmented.
// flags: 1=ROPE, 2=SCALE, 4=V^T out (LDS-transposed coalesced store),
//        8=fp32 out, 16=bn-pair (two 128-col tiles per block, K=128 only)
struct GSeg {
  const short* A;
  const short* W;
  const float* bias0;
  const float* bias1;
  void* outp;
  int lda, ldw, bsplit, ropestart, ldo, ocol, K, flags;
};
struct GArgs { GSeg s[3]; int start[4]; };

__global__ __launch_bounds__(256, 2) void gemm_rt(GArgs ga, const int* __restrict__ pos) {
  int by = blockIdx.y;
  int si = (by >= ga.start[1]) + (by >= ga.start[2]);
  const GSeg sg = ga.s[si];
  int tid = threadIdx.x, w = tid >> 6, lane = tid & 63;
  int quad = lane >> 4, l16 = lane & 15;
  bool ropeF = sg.flags & 1, scaleF = sg.flags & 2;
  bool vtF = sg.flags & 4, f32F = sg.flags & 8, pairF = sg.flags & 16;
  int bm = blockIdx.x * 128;
  int bn = (by - ga.start[si]) * (pairF ? 256 : 128);
  int wm = (w & 1) * 64, wn = (w >> 1) * 64;
  int lda = sg.lda, ldw = sg.ldw;

  __shared__ short At[2][128 * 64];
  __shared__ short Bt[2][128 * 64];

  int srow[4], soff[4];
#pragma unroll
  for (int j = 0; j < 4; j++) {
    int r = w * 32 + j * 8 + (lane >> 3);
    srow[j] = r;
    soff[j] = ((lane & 7) ^ (r & 7)) << 3;
  }
  const short* Ag = sg.A + (size_t)bm * lda;
  const short* Wg = sg.W + (size_t)bn * ldw;

  float4v acc[4][4];
  float4v z = {0.f, 0.f, 0.f, 0.f};
#pragma unroll
  for (int mi = 0; mi < 4; mi++)
#pragma unroll
    for (int ni = 0; ni < 4; ni++) acc[mi][ni] = z;

  auto comp = [&](const short* Ab, const short* Bb) {
#pragma unroll
    for (int ks = 0; ks < 2; ks++) {
      short8 af[4], bf[4];
#pragma unroll
      for (int mi = 0; mi < 4; mi++) {
        int row = wm + mi * 16 + l16;
        af[mi] = *(const short8*)&Ab[(row << 6) + ((((ks << 2) + quad) ^ (row & 7)) << 3)];
      }
#pragma unroll
      for (int ni = 0; ni < 4; ni++) {
        int row = wn + ni * 16 + l16;
        bf[ni] = *(const short8*)&Bb[(row << 6) + ((((ks << 2) + quad) ^ (row & 7)) << 3)];
      }
#pragma unroll
      for (int mi = 0; mi < 4; mi++)
#pragma unroll
        for (int ni = 0; ni < 4; ni++)
          acc[mi][ni] = MFMA16(af[mi], bf[ni], acc[mi][ni]);
    }
  };

  // ---- epilogue (runtime flags; block-uniform branches) ----
  auto epi = [&](int bnX) {
    if (vtF) {
      // transpose 128x128 tile through LDS (At as scratch), coalesced store
      __syncthreads();  // all waves done reading At/Bt
      short* T = &At[0][0];  // 32KB: T[col*128 + rotated_row]
#pragma unroll
      for (int ni = 0; ni < 4; ni++) {
        int col = wn + ni * 16 + l16;
        float bv = sg.bias0[bnX + col];
#pragma unroll
        for (int mi = 0; mi < 4; mi++) {
          int row0 = wm + mi * 16 + quad * 4;
          int rr = (row0 + ((col & 15) << 3)) & 127;
          short4v ov;
#pragma unroll
          for (int r = 0; r < 4; r++) ov[r] = f2bf(acc[mi][ni][r] + bv);
          *(short4v*)&T[col * 128 + rr] = ov;
        }
      }
      __syncthreads();
      int bidx = bm >> 11, s0 = bm & 2047;
      int sc = tid & 15;
#pragma unroll
      for (int cc = 0; cc < 8; cc++) {
        int c = cc * 16 + (tid >> 4);
        int rr = ((sc + (c & 15)) << 3) & 127;
        short8 v = *(const short8*)&T[c * 128 + rr];
        *(short8*)((short*)sg.outp + ((size_t)(bidx * 1536 + bnX + c)) * 2048 +
                   s0 + (sc << 3)) = v;
      }
      return;
    }
#pragma unroll
    for (int ni = 0; ni < 4; ni++) {
      int col = bnX + wn + ni * 16 + l16;
      float bv = (col < sg.bsplit) ? sg.bias0[col] : sg.bias1[col - sg.bsplit];
      float fr = 0.f;
      bool dorope = ropeF && (col >= sg.ropestart);
      if (dorope) {
        int ri = (col - sg.ropestart) & ~1;
        fr = exp2f((float)ri * (-13.287712379549449f / 768.0f));
      }
#pragma unroll
      for (int mi = 0; mi < 4; mi++) {
        int row0 = bm + wm + mi * 16 + quad * 4;
#pragma unroll
        for (int r = 0; r < 4; r++) {
          int row = row0 + r;
          float v = acc[mi][ni][r] + bv;
          if (ropeF) {
            float pv = __shfl_xor(v, 1, 64);
            if (dorope) {
              float ang = (float)pos[row & 2047] * fr;
              float sn, cs;
              __sincosf(ang, &sn, &cs);
              v = (col & 1) ? (pv * sn + v * cs) : (v * cs - pv * sn);
            }
          }
          if (scaleF) v *= 0.12751743f;  // (1/sqrt(128)) * log2(e)
          if (f32F)
            ((float*)sg.outp)[(size_t)row * sg.ldo + sg.ocol + col] = v;
          else
            ((short*)sg.outp)[(size_t)row * sg.ldo + sg.ocol + col] = f2bf(v);
        }
      }
    }
  };

  int nk = sg.K >> 6;
  if (nk == 2) {
    // thin-K fast path: stage K=128 entirely, one barrier
    auto stageB = [&](const short* Wg2) {
#pragma unroll
      for (int j = 0; j < 4; j++) {
        glds16(Wg2 + (size_t)srow[j] * ldw + soff[j], &Bt[0][(w * 32 + j * 8) * 64]);
        glds16(Wg2 + (size_t)srow[j] * ldw + 64 + soff[j], &Bt[1][(w * 32 + j * 8) * 64]);
      }
    };
#pragma unroll
    for (int j = 0; j < 4; j++) {
      glds16(Ag + (size_t)srow[j] * lda + soff[j], &At[0][(w * 32 + j * 8) * 64]);
      glds16(Ag + (size_t)srow[j] * lda + 64 + soff[j], &At[1][(w * 32 + j * 8) * 64]);
    }
    stageB(Wg);
    __syncthreads();
    comp(At[0], Bt[0]);
    comp(At[1], Bt[1]);
    if (pairF) {
      __syncthreads();            // waves done reading Bt
      stageB(Wg + (size_t)128 * ldw);  // DMA next B tile under epilogue
      epi(bn);
#pragma unroll
      for (int mi = 0; mi < 4; mi++)
#pragma unroll
        for (int ni = 0; ni < 4; ni++) acc[mi][ni] = z;
      __syncthreads();            // drains glds16
      comp(At[0], Bt[0]);
      comp(At[1], Bt[1]);
      epi(bn + 128);
    } else {
      epi(bn);
    }
  } else {
#pragma unroll
    for (int j = 0; j < 4; j++)
      glds16(Ag + (size_t)srow[j] * lda + soff[j], &At[0][(w * 32 + j * 8) * 64]);
#pragma unroll
    for (int j = 0; j < 4; j++)
      glds16(Wg + (size_t)srow[j] * ldw + soff[j], &Bt[0][(w * 32 + j * 8) * 64]);
    for (int it = 0; it < nk; it++) {
      __syncthreads();
      if (it + 1 < nk) {
        int kt = (it + 1) << 6, nb = (it + 1) & 1;
#pragma unroll
        for (int j = 0; j < 4; j++)
          glds16(Ag + (size_t)srow[j] * lda + kt + soff[j],
                 &At[nb][(w * 32 + j * 8) * 64]);
#pragma unroll
        for (int j = 0; j < 4; j++)
          glds16(Wg + (size_t)srow[j] * ldw + kt + soff[j],
                 &Bt[nb][(w * 32 + j * 8) * 64]);
      }
      comp(At[it & 1], Bt[it & 1]);
    }
    epi(bn);
  }
}

// ---------- causal flash attention: 128-q blocks, 32 q/wave, no-max softmax ----
// grid 768 (1-D, global LPT order; (b,h) implicitly XCD-pinned since
// o%8 == g%8 for all ranks), 256 thr.
__global__ __launch_bounds__(256, 2) void mla_attn(const short* __restrict__ Q,
                                                   const short* __restrict__ K,
                                                   const short* __restrict__ Vt,
                                                   short* __restrict__ O) {
  const int ld = 1536, SEQ = 2048;
  int tid = threadIdx.x, w = tid >> 6, lane = tid & 63;
  int quad = lane >> 4, l16 = lane & 15;
  int o = (int)blockIdx.x;
  int rank = o / 48;
  int g = o - rank * 48;
  int qt = (15 - rank) * 128;
  int hh = g % 12, b = g / 12;
  int qw = qt + w * 32;

  __shared__ short Kt[2][64 * 128];
  __shared__ short Vl[2][128 * 64];
  __shared__ short Pm[4][32 * 64];
  char* pwB = (char*)Pm[w];

  int kgo[4], vgo[4];
#pragma unroll
  for (int j = 0; j < 4; j++) {
    int rk = (w * 4 + j) * 4 + (lane >> 4);
    kgo[j] = rk * ld + (((lane & 15) ^ (rk & 7)) << 3);
    int rv = (w * 4 + j) * 8 + (lane >> 3);
    vgo[j] = rv * SEQ + (((lane & 7) ^ (rv & 7)) << 3);
  }
  const short* Kg = K + (size_t)b * SEQ * ld + hh * 128;
  const short* Vg = Vt + (size_t)(b * 12 + hh) * 128 * SEQ;

  short8 qf[2][4];
  {
    const short* Qg = Q + (size_t)(b * SEQ + qw + l16) * ld + hh * 128 + quad * 8;
#pragma unroll
    for (int nf = 0; nf < 2; nf++)
#pragma unroll
      for (int ks = 0; ks < 4; ks++)
        qf[nf][ks] = *(const short8*)(Qg + (size_t)nf * 16 * ld + ks * 32);
  }

  // ---- loop-invariant LDS byte offsets ----
  int koff[4][4], voff[2][8], pfo[2][2], pwo[2][4];
#pragma unroll
  for (int ks = 0; ks < 4; ks++)
#pragma unroll
    for (int mf = 0; mf < 4; mf++) {
      int row = mf * 16 + l16;
      koff[ks][mf] = row * 256 + ((((ks << 2) + quad) ^ (row & 7)) << 4);
    }
#pragma unroll
  for (int t = 0; t < 2; t++) {
#pragma unroll
    for (int df = 0; df < 8; df++) {
      int vr = df * 16 + l16;
      voff[t][df] = vr * 128 + ((((t << 2) + quad) ^ (vr & 7)) << 4);
    }
#pragma unroll
    for (int mq = 0; mq < 2; mq++)
      pfo[t][mq] = (mq * 16 + l16) * 128 + ((((t << 2) + quad) ^ (l16 & 7)) << 4);
#pragma unroll
    for (int mf = 0; mf < 4; mf++) {
      int p = (mf * 2 + (quad >> 1)) ^ (l16 & 7);
      pwo[t][mf] = (t * 16 + l16) * 128 + (p << 4) + ((quad & 1) << 3);
    }
  }

  float4v z = {0.f, 0.f, 0.f, 0.f};
  float4v oacc[2][8];
#pragma unroll
  for (int mq = 0; mq < 2; mq++)
#pragma unroll
    for (int df = 0; df < 8; df++) oacc[mq][df] = z;
  float l_i[2] = {0.f, 0.f};

#pragma unroll
  for (int j = 0; j < 4; j++) glds16(Kg + kgo[j], &Kt[0][(w * 4 + j) * 512]);
#pragma unroll
  for (int j = 0; j < 4; j++) glds16(Vg + vgo[j], &Vl[0][(w * 4 + j) * 512]);

  int ntiles = (qt >> 6) + 2;  // always even

#define ATTN_TILE(IT, NB, NB1)                                                 \
  do {                                                                         \
    int kt = (IT) << 6;                                                        \
    __syncthreads();                                                           \
    if ((IT) + 1 < ntiles) {                                                   \
      const short* kn = Kg + (size_t)(kt + 64) * ld;                           \
      const short* vn = Vg + (kt + 64);                                        \
      _Pragma("unroll") for (int j = 0; j < 4; j++)                            \
          glds16(kn + kgo[j], &Kt[NB1][(w * 4 + j) * 512]);                    \
      _Pragma("unroll") for (int j = 0; j < 4; j++)                            \
          glds16(vn + vgo[j], &Vl[NB1][(w * 4 + j) * 512]);                    \
    }                                                                          \
    if (kt <= qw + 31) {                                                       \
      const char* Kb = (const char*)Kt[NB];                                    \
      const char* Vb = (const char*)Vl[NB];                                    \
      float4v sf[4][2];                                                        \
      __builtin_amdgcn_s_setprio(1);                                           \
      _Pragma("unroll") for (int mf = 0; mf < 4; mf++) {                       \
        short8 a = *(const short8*)(Kb + koff[0][mf]);                         \
        sf[mf][0] = MFMA16(a, qf[0][0], z);                                    \
        sf[mf][1] = MFMA16(a, qf[1][0], z);                                    \
      }                                                                        \
      _Pragma("unroll") for (int ks = 1; ks < 4; ks++) {                       \
        _Pragma("unroll") for (int mf = 0; mf < 4; mf++) {                     \
          short8 a = *(const short8*)(Kb + koff[ks][mf]);                      \
          sf[mf][0] = MFMA16(a, qf[0][ks], sf[mf][0]);                         \
          sf[mf][1] = MFMA16(a, qf[1][ks], sf[mf][1]);                         \
        }                                                                      \
      }                                                                        \
      __builtin_amdgcn_s_setprio(0);                                           \
      if (kt + 63 > qw) {                                                      \
        _Pragma("unroll") for (int mf = 0; mf < 4; mf++) {                     \
          int key = kt + mf * 16 + quad * 4;                                   \
          _Pragma("unroll") for (int nf = 0; nf < 2; nf++) {                   \
            int q = qw + nf * 16 + l16;                                        \
            _Pragma("unroll") for (int r = 0; r < 4; r++)                      \
                if (key + r > q) sf[mf][nf][r] = -3e38f;                       \
          }                                                                    \
        }                                                                      \
      }                                                                        \
      _Pragma("unroll") for (int nf = 0; nf < 2; nf++) {                       \
        float ps = 0.f;                                                        \
        _Pragma("unroll") for (int mf = 0; mf < 4; mf++)                       \
            _Pragma("unroll") for (int r = 0; r < 4; r++) {                    \
          float e = exp2f(sf[mf][nf][r]);                                      \
          sf[mf][nf][r] = e;                                                   \
          ps += e;                                                             \
        }                                                                      \
        l_i[nf] += ps;                                                         \
        _Pragma("unroll") for (int mf = 0; mf < 4; mf++) {                     \
          int2v pk;                                                            \
          pk[0] = cvtpk(sf[mf][nf][0], sf[mf][nf][1]);                         \
          pk[1] = cvtpk(sf[mf][nf][2], sf[mf][nf][3]);                         \
          *(int2v*)(pwB + pwo[nf][mf]) = pk;                                   \
        }                                                                      \
      }                                                                        \
      __builtin_amdgcn_s_setprio(1);                                           \
      _Pragma("unroll") for (int t = 0; t < 2; t++) {                          \
        short8 pf0 = *(const short8*)(pwB + pfo[t][0]);                        \
        short8 pf1 = *(const short8*)(pwB + pfo[t][1]);                        \
        _Pragma("unroll") for (int df = 0; df < 8; df++) {                     \
          short8 vf = *(const short8*)(Vb + voff[t][df]);                      \
          oacc[0][df] = MFMA16(pf0, vf, oacc[0][df]);                          \
          oacc[1][df] = MFMA16(pf1, vf, oacc[1][df]);                          \
        }                                                                      \
      }                                                                        \
      __builtin_amdgcn_s_setprio(0);                                           \
    }                                                                          \
  } while (0)

  for (int it = 0; it < ntiles; it += 2) {
    ATTN_TILE(it, 0, 1);
    ATTN_TILE(it + 1, 1, 0);
  }
#undef ATTN_TILE

  // ---- epilogue: reduce l across quads, scale, store ----
  short* Og = O + (size_t)(b * SEQ + qw) * ld + hh * 128;
#pragma unroll
  for (int mq = 0; mq < 2; mq++) {
    float l = l_i[mq];
    l += __shfl_xor(l, 16, 64);
    l += __shfl_xor(l, 32, 64);
    float linv = 1.0f / l;
    float lb[4];
#pragma unroll
    for (int r = 0; r < 4; r++) lb[r] = __shfl(linv, (quad << 2) + r, 64);
#pragma unroll
    for (int df = 0; df < 8; df++)
#pragma unroll
      for (int r = 0; r < 4; r++)
        Og[(size_t)(mq * 16 + (quad << 2) + r) * ld + df * 16 + l16] =
            f2bf(oacc[mq][df][r] * lb[r]);
  }
}

// ---------- launcher ----------
extern "C" void kernel_launch(void* const* d_in, const int* in_sizes, int n_in,
                              void* d_out, int out_size, void* d_ws, size_t ws_size,
                              hipStream_t stream) {
  const int S = 2048, DM = 768, DL = 128, HD = 1536;
  const int M = 4 * S;  // 8192
  const int BIG = 1 << 28;

  const float* x = (const float*)d_in[0];
  const int* pos = (const int*)d_in[1];
  const float* W_dkv = (const float*)d_in[2];
  const float* b_dkv = (const float*)d_in[3];
  const float* W_dq = (const float*)d_in[4];
  const float* b_dq = (const float*)d_in[5];
  const float* W_uk_nope = (const float*)d_in[6];
  const float* b_uk_nope = (const float*)d_in[7];
  const float* W_uv = (const float*)d_in[8];
  const float* b_uv = (const float*)d_in[9];
  const float* W_uq_nope = (const float*)d_in[10];
  const float* b_uq_nope = (const float*)d_in[11];
  const float* W_uq_rope = (const float*)d_in[12];
  const float* b_uq_rope = (const float*)d_in[13];
  const float* W_uk_rope = (const float*)d_in[14];
  const float* b_uk_rope = (const float*)d_in[15];
  const float* W_o = (const float*)d_in[16];
  const float* b_o = (const float*)d_in[17];

  char* p = (char*)d_ws;
  size_t off = 0;
  auto take = [&](size_t nelem) -> short* {
    short* r = (short*)(p + off);
    off += (nelem * 2 + 255) & ~(size_t)255;
    return r;
  };
  short* xb = take((size_t)M * DM);
  short* Wdq = take(DL * DM);
  short* Wdkv = take(DL * DM);
  short* Wuqnope = take(768 * DL);
  short* Wuqrope = take(768 * DL);
  short* Wuknope = take(768 * DL);
  short* Wuv = take(1536 * DL);
  short* Wukrope = take(768 * DM);
  short* Wo = take(768 * 1536);
  short* Cm = take((size_t)M * 256);  // [C_q | C_kv]
  short* Qm = take((size_t)M * HD);
  short* Km = take((size_t)M * HD);
  short* Vtm = take((size_t)M * HD);  // V^T: [b][h*128+d][s]
  short* Om = take((size_t)M * HD);
  if (off > ws_size) return;

  CastArgs ca;
  const float* srcs[9] = {x, W_dq, W_dkv, W_uq_nope, W_uq_rope, W_uk_nope, W_uv, W_uk_rope, W_o};
  short* dsts[9] = {xb, Wdq, Wdkv, Wuqnope, Wuqrope, Wuknope, Wuv, Wukrope, Wo};
  int ns[9] = {M * DM, DL * DM, DL * DM, 768 * DL, 768 * DL, 768 * DL, 1536 * DL, 768 * DM, 768 * 1536};
  ca.start[0] = 0;
  for (int i = 0; i < 9; i++) {
    ca.seg[i].src = srcs[i];
    ca.seg[i].dst = dsts[i];
    ca.seg[i].n4 = ns[i] / 4;
    ca.start[i + 1] = ca.start[i] + (ca.seg[i].n4 + 255) / 256;
  }
  castk<<<dim3(ca.start[9]), dim3(256), 0, stream>>>(ca);

  // ---- launch 1: C (N=256,K=768) || rope(k_rope) (N=768,K=768) ----
  GArgs g1;
  g1.s[0].A = xb;   g1.s[0].W = Wdq;      g1.s[0].bias0 = b_dq;      g1.s[0].bias1 = b_dkv;
  g1.s[0].outp = Cm; g1.s[0].lda = DM; g1.s[0].ldw = DM; g1.s[0].bsplit = 128;
  g1.s[0].ropestart = 0; g1.s[0].ldo = 256; g1.s[0].ocol = 0; g1.s[0].K = DM; g1.s[0].flags = 0;
  g1.s[1].A = xb;   g1.s[1].W = Wukrope;  g1.s[1].bias0 = b_uk_rope; g1.s[1].bias1 = b_uk_rope;
  g1.s[1].outp = Km; g1.s[1].lda = DM; g1.s[1].ldw = DM; g1.s[1].bsplit = BIG;
  g1.s[1].ropestart = 0; g1.s[1].ldo = HD; g1.s[1].ocol = 768; g1.s[1].K = DM; g1.s[1].flags = 1;
  g1.s[2] = g1.s[1];
  g1.start[0] = 0; g1.start[1] = 2; g1.start[2] = 8; g1.start[3] = 8;
  gemm_rt<<<dim3(M / 128, 8), dim3(256), 0, stream>>>(g1, pos);

  // ---- launch 2: Q (N=1536,paired) || k_nope (N=768,paired) || V^T (N=1536) ----
  GArgs g2;
  g2.s[0].A = Cm;   g2.s[0].W = Wuqnope;  g2.s[0].bias0 = b_uq_nope; g2.s[0].bias1 = b_uq_rope;
  g2.s[0].outp = Qm; g2.s[0].lda = 256; g2.s[0].ldw = DL; g2.s[0].bsplit = 768;
  g2.s[0].ropestart = 768; g2.s[0].ldo = HD; g2.s[0].ocol = 0; g2.s[0].K = DL;
  g2.s[0].flags = 1 | 2 | 16;
  g2.s[1].A = Cm + 128; g2.s[1].W = Wuknope; g2.s[1].bias0 = b_uk_nope; g2.s[1].bias1 = b_uk_nope;
  g2.s[1].outp = Km; g2.s[1].lda = 256; g2.s[1].ldw = DL; g2.s[1].bsplit = BIG;
  g2.s[1].ropestart = 0; g2.s[1].ldo = HD; g2.s[1].ocol = 0; g2.s[1].K = DL;
  g2.s[1].flags = 16;
  g2.s[2].A = Cm + 128; g2.s[2].W = Wuv;   g2.s[2].bias0 = b_uv;      g2.s[2].bias1 = b_uv;
  g2.s[2].outp = Vtm; g2.s[2].lda = 256; g2.s[2].ldw = DL; g2.s[2].bsplit = BIG;
  g2.s[2].ropestart = 0; g2.s[2].ldo = 0; g2.s[2].ocol = 0; g2.s[2].K = DL;
  g2.s[2].flags = 4;
  g2.start[0] = 0; g2.start[1] = 6; g2.start[2] = 9; g2.start[3] = 21;
  gemm_rt<<<dim3(M / 128, 21), dim3(256), 0, stream>>>(g2, pos);

  // ---- attention: 768 blocks, global longest-first (LPT) order ----
  mla_attn<<<dim3(768), dim3(256), 0, stream>>>(Qm, Km, Vtm, Om);

  // ---- launch 3: out = O @ W_o^T + b_o (N=768, K=1536, fp32 out) ----
  GArgs g3;
  g3.s[0].A = Om;   g3.s[0].W = Wo;       g3.s[0].bias0 = b_o;       g3.s[0].bias1 = b_o;
  g3.s[0].outp = d_out; g3.s[0].lda = HD; g3.s[0].ldw = HD; g3.s[0].bsplit = BIG;
  g3.s[0].ropestart = 0; g3.s[0].ldo = 768; g3.s[0].ocol = 0; g3.s[0].K = HD; g3.s[0].flags = 8;
  g3.s[1] = g3.s[0];
  g3.s[2] = g3.s[0];
  g3.start[0] = 0; g3.start[1] = 6; g3.start[2] = 6; g3.start[3] = 6;
  gemm_rt<<<dim3(M / 128, 6), dim3(256), 0, stream>>>(g3, pos);
}